// Round 2
// baseline (1074.817 us; speedup 1.0000x reference)
//
#include <hip/hip_runtime.h>
#include <math.h>

// global_powermean_pooling, P = 2.0
//   out[g, d] = sqrt( mean_{n : batch[n]==g} x[n, d]^2 ),  empty segment -> 0
// x: [N, 128] fp32, batch: [N] int32 sorted ascending in [0, G)
//
// R3 — INSTRUMENTED ROUND (dur_us is sacrificial; probes to be removed next round).
// Established: the 2GB ws poison fill (~323us) is unconditional & timed; the pool
// loop runs at ~1.6 TB/s (4x off roofline) under two different structures.
// This round: (1) real pipeline = coordinated-sweep kernel (dense sweeping read
// front like the fill/copy ubench) + atomic combine; (2) ProbeA = raw dense
// grid-stride read of x, 4 passes (>321us so counters surface); (3) ProbeB =
// clone of the old per-graph streaming loop, 1.25 passes (counters for the old
// pattern: FETCH amplification? occupancy? VALUBusy?).

#define D_FEAT 128
#define DV 32            // float4 per row
#define SWEEP_GRID 2048
#define CHUNK 64         // rows per sweep chunk (32 KB)

typedef float f32x4 __attribute__((ext_vector_type(4)));

// ---- Kernel A: segment offsets (proven in R1) ---------------------------
__global__ __launch_bounds__(256) void seg_offsets_kernel(
    const int* __restrict__ batch, int* __restrict__ off, int N, int G)
{
    int i = blockIdx.x * blockDim.x + threadIdx.x;
    if (i >= N) return;
    int cur = batch[i];
    if (i == 0) {
        for (int g = 0; g <= cur; ++g) off[g] = 0;
    } else {
        int prev = batch[i - 1];
        for (int g = prev + 1; g <= cur; ++g) off[g] = i;
    }
    if (i == N - 1) {
        for (int g = cur + 1; g <= G; ++g) off[g] = N;
    }
}

// ---- Kernel Z: zero the output accumulator ------------------------------
__global__ __launch_bounds__(256) void zero_out_kernel(f32x4* __restrict__ out4, int n4)
{
    int i = blockIdx.x * 256 + threadIdx.x;
    if (i < n4) out4[i] = (f32x4)0.f;
}

// ---- Kernel S: coordinated-sweep power-sum (the real pool) --------------
// Grid-stride over 64-row chunks: at any instant the 2048 resident blocks read
// a dense ~64MB window that sweeps x front-to-back (mimics the 6.3TB/s fill).
// Within a chunk, runs (graph boundaries) are block-uniform via off[], so the
// LDS reduce + atomic flush per run has no divergent barriers.
__global__ __launch_bounds__(256) void global_powermean_pooling_44126493999223_kernel(
    const f32x4* __restrict__ x4,
    const int*   __restrict__ batch,
    const int*   __restrict__ off,
    float*       __restrict__ out,
    int N)
{
    const int tid  = threadIdx.x;
    const int fg   = tid & 31;   // float4 index within 128-wide row
    const int lane = tid >> 5;   // node-lane 0..7

    __shared__ f32x4 red[256];

    const int nchunks = (N + CHUNK - 1) / CHUNK;
    for (int c = blockIdx.x; c < nchunks; c += SWEEP_GRID) {
        const int rs = c * CHUNK;
        const int re = (rs + CHUNK < N) ? rs + CHUNK : N;
        int cur = rs;
        int g = batch[rs];                 // block-uniform broadcast load
        while (cur < re) {
            const int ge = off[g + 1];
            const int run_end = (ge < re) ? ge : re;

            f32x4 a0 = (f32x4)0.f, a1 = (f32x4)0.f, a2 = (f32x4)0.f, a3 = (f32x4)0.f;
            int r = cur + lane;
            for (; r + 24 < run_end; r += 32) {
                f32x4 v0 = x4[(size_t)(r     ) * DV + fg];
                f32x4 v1 = x4[(size_t)(r +  8) * DV + fg];
                f32x4 v2 = x4[(size_t)(r + 16) * DV + fg];
                f32x4 v3 = x4[(size_t)(r + 24) * DV + fg];
                a0 += v0 * v0; a1 += v1 * v1; a2 += v2 * v2; a3 += v3 * v3;
            }
            for (; r < run_end; r += 8) {
                f32x4 v = x4[(size_t)r * DV + fg];
                a0 += v * v;
            }
            a0 += a1; a2 += a3; a0 += a2;

            red[tid] = a0;
            __syncthreads();
            if (lane < 4) red[tid] += red[tid + 128];
            __syncthreads();
            if (lane < 2) red[tid] += red[tid + 64];
            __syncthreads();
            if (lane == 0) {
                f32x4 s = red[tid] + red[tid + 32];
                float* dst = out + (size_t)g * D_FEAT + fg * 4;
                atomicAdd(dst + 0, s[0]);
                atomicAdd(dst + 1, s[1]);
                atomicAdd(dst + 2, s[2]);
                atomicAdd(dst + 3, s[3]);
            }
            __syncthreads();               // red reused next run
            cur = run_end;
            if (cur < re) g = batch[cur];  // rare (~0.26/chunk), uniform
        }
    }
}

// ---- Kernel F: finalize sqrt(sum / count) -------------------------------
__global__ __launch_bounds__(128) void finalize_kernel(
    const int* __restrict__ off, float* __restrict__ out)
{
    const int g = blockIdx.x;
    const int d = threadIdx.x;
    const int cnt = off[g + 1] - off[g];
    const size_t i = (size_t)g * D_FEAT + d;
    const float v = out[i];
    out[i] = (cnt > 0) ? sqrtf(v / (float)cnt) : 0.f;
}

// ---- ProbeA: raw dense grid-stride read, 4 passes (2.05 GB) -------------
// Measures the in-harness read ceiling with a copy-ubench access pattern.
__global__ __launch_bounds__(256) void probeA_dense_read_kernel(
    const f32x4* __restrict__ x4, float* __restrict__ wsout, int n4)
{
    const int t = blockIdx.x * 256 + threadIdx.x;
    const int S = SWEEP_GRID * 256;
    f32x4 a0 = (f32x4)0.f, a1 = (f32x4)0.f, a2 = (f32x4)0.f, a3 = (f32x4)0.f;
    for (int pass = 0; pass < 4; ++pass) {
        int i = t;
        for (; i + 3 * S < n4; i += 4 * S) {
            f32x4 v0 = x4[(size_t)i];
            f32x4 v1 = x4[(size_t)(i +     S)];
            f32x4 v2 = x4[(size_t)(i + 2 * S)];
            f32x4 v3 = x4[(size_t)(i + 3 * S)];
            a0 += v0 * v0; a1 += v1 * v1; a2 += v2 * v2; a3 += v3 * v3;
        }
        for (; i < n4; i += S) { f32x4 v = x4[(size_t)i]; a0 += v * v; }
    }
    a0 += a1; a2 += a3; a0 += a2;
    wsout[t] = a0[0] + a0[1] + a0[2] + a0[3];
}

// ---- ProbeB: clone of the R1 per-graph streaming loop, 1.25 passes ------
// Surfaces counters (FETCH_SIZE, Occupancy, VALUBusy) for the old pattern.
__global__ __launch_bounds__(256) void probeB_pergraph_read_kernel(
    const f32x4* __restrict__ x4, const int* __restrict__ off,
    float* __restrict__ wsout)
{
    const int g    = blockIdx.x;
    const int tid  = threadIdx.x;
    const int fg   = tid & 31;
    const int lane = tid >> 5;

    const int start = off[g];
    const int end   = off[g + 1];
    const int end2  = start + ((end - start) >> 2);   // second partial pass

    f32x4 a0 = (f32x4)0.f, a1 = (f32x4)0.f, a2 = (f32x4)0.f, a3 = (f32x4)0.f;
    for (int pass = 0; pass < 2; ++pass) {
        const int e = (pass == 0) ? end : end2;
        int r = start + lane;
        for (; r + 24 < e; r += 32) {
            f32x4 v0 = x4[(size_t)(r     ) * DV + fg];
            f32x4 v1 = x4[(size_t)(r +  8) * DV + fg];
            f32x4 v2 = x4[(size_t)(r + 16) * DV + fg];
            f32x4 v3 = x4[(size_t)(r + 24) * DV + fg];
            a0 += v0 * v0; a1 += v1 * v1; a2 += v2 * v2; a3 += v3 * v3;
        }
        for (; r < e; r += 8) { f32x4 v = x4[(size_t)r * DV + fg]; a0 += v * v; }
    }
    a0 += a1; a2 += a3; a0 += a2;

    __shared__ f32x4 red[256];
    red[tid] = a0;
    __syncthreads();
    if (lane < 4) red[tid] += red[tid + 128];
    __syncthreads();
    if (lane < 2) red[tid] += red[tid + 64];
    __syncthreads();
    if (lane == 0) {
        f32x4 s = red[tid] + red[tid + 32];
        ((f32x4*)wsout)[(size_t)g * DV + fg] = s;
    }
}

extern "C" void kernel_launch(void* const* d_in, const int* in_sizes, int n_in,
                              void* d_out, int out_size, void* d_ws, size_t ws_size,
                              hipStream_t stream) {
    const float* x     = (const float*)d_in[0];
    const int*   batch = (const int*)d_in[1];
    float*       out   = (float*)d_out;

    const int N = in_sizes[1];           // 1,000,000 nodes
    const int G = out_size / D_FEAT;     // 4096 graphs

    int*   off       = (int*)d_ws;                                  // (G+1) ints
    float* probeA_ws = (float*)((char*)d_ws + (16u << 20));         // 2 MB
    float* probeB_ws = (float*)((char*)d_ws + (32u << 20));         // 2 MB

    const int n4 = G * DV;

    // Real pipeline (cold-cache, same state as R1/R2 for comparability):
    seg_offsets_kernel<<<(N + 255) / 256, 256, 0, stream>>>(batch, off, N, G);
    zero_out_kernel<<<(n4 + 255) / 256, 256, 0, stream>>>((f32x4*)out, n4);
    global_powermean_pooling_44126493999223_kernel
        <<<SWEEP_GRID, 256, 0, stream>>>((const f32x4*)x, batch, off, out, N);
    finalize_kernel<<<G, 128, 0, stream>>>(off, out);

    // Diagnostics (AFTER the real pipeline; write to ws; removed next round):
    probeA_dense_read_kernel<<<SWEEP_GRID, 256, 0, stream>>>(
        (const f32x4*)x, probeA_ws, N * DV);
    probeB_pergraph_read_kernel<<<G, 256, 0, stream>>>(
        (const f32x4*)x, off, probeB_ws);
}

// Round 3
// 659.379 us; speedup vs baseline: 1.6300x; 1.6300x over previous
//
#include <hip/hip_runtime.h>
#include <math.h>

// global_powermean_pooling, P = 2.0
//   out[g, d] = sqrt( mean_{n : batch[n]==g} x[n, d]^2 ),  empty segment -> 0
// x: [N, 128] fp32, batch: [N] int32 sorted ascending in [0, G)
//
// R4 — clean sweep pipeline (probes removed).
// Evidence so far:
//   * The harness's 2GB ws poison fill (~323us @ 6.3TB/s) is unconditional and
//     inside the timed window — a fixed ~323us floor term.
//   * ProbeA (R3): dense grid-stride read delivers ~6.1 TB/s effective
//     (3.05 TB/s HBM + ~50% LLC hits on re-passes) — the read path is fine.
//   * R1/R2's per-graph private streams ran ~1.6 TB/s — scattered 2048-stream
//     layout was the problem, not MSHRs / environment.
// Structure:
//   Kernel A: off[g] = lower_bound(batch, g)  (boundary scatter, ws)
//   Kernel Z: zero out[] (atomic accumulator base)
//   Kernel S: coordinated sweep — grid-stride over contiguous 64-row chunks so
//             the chip-wide read front is dense and sweeps x front-to-back
//             (ProbeA's access pattern). Per-run LDS reduce + f32 atomicAdd.
//   Kernel F: out = sqrt(out / count)

#define D_FEAT 128
#define DV 32            // float4 per row
#define SWEEP_GRID 2048  // 8 blocks/CU
#define CHUNK 64         // rows per sweep chunk (32 KB)

typedef float f32x4 __attribute__((ext_vector_type(4)));

// ---- Kernel A: segment offsets ------------------------------------------
__global__ __launch_bounds__(256) void seg_offsets_kernel(
    const int* __restrict__ batch, int* __restrict__ off, int N, int G)
{
    int i = blockIdx.x * blockDim.x + threadIdx.x;
    if (i >= N) return;
    int cur = batch[i];
    if (i == 0) {
        for (int g = 0; g <= cur; ++g) off[g] = 0;
    } else {
        int prev = batch[i - 1];
        for (int g = prev + 1; g <= cur; ++g) off[g] = i;
    }
    if (i == N - 1) {
        for (int g = cur + 1; g <= G; ++g) off[g] = N;
    }
}

// ---- Kernel Z: zero the output accumulator ------------------------------
__global__ __launch_bounds__(256) void zero_out_kernel(f32x4* __restrict__ out4, int n4)
{
    int i = blockIdx.x * 256 + threadIdx.x;
    if (i < n4) out4[i] = (f32x4)0.f;
}

// ---- Kernel S: coordinated-sweep power-sum ------------------------------
// At any instant the 2048 resident blocks read a dense ~64MB window that
// sweeps x front-to-back. Runs (graph boundaries) are block-uniform via off[],
// so reduce/flush has no divergent barriers. ~0.26 boundary crossings per
// chunk on average (counts ~244, chunk 64).
__global__ __launch_bounds__(256) void global_powermean_pooling_44126493999223_kernel(
    const f32x4* __restrict__ x4,
    const int*   __restrict__ batch,
    const int*   __restrict__ off,
    float*       __restrict__ out,
    int N)
{
    const int tid  = threadIdx.x;
    const int fg   = tid & 31;   // float4 index within 128-wide row
    const int lane = tid >> 5;   // node-lane 0..7

    __shared__ f32x4 red[256];

    const int nchunks = (N + CHUNK - 1) / CHUNK;
    for (int c = blockIdx.x; c < nchunks; c += SWEEP_GRID) {
        const int rs = c * CHUNK;
        const int re = (rs + CHUNK < N) ? rs + CHUNK : N;
        int cur = rs;
        int g = batch[rs];                 // block-uniform broadcast load
        while (cur < re) {
            const int ge = off[g + 1];
            const int run_end = (ge < re) ? ge : re;

            f32x4 a0 = (f32x4)0.f, a1 = (f32x4)0.f, a2 = (f32x4)0.f, a3 = (f32x4)0.f;
            int r = cur + lane;
            for (; r + 24 < run_end; r += 32) {
                f32x4 v0 = x4[(size_t)(r     ) * DV + fg];
                f32x4 v1 = x4[(size_t)(r +  8) * DV + fg];
                f32x4 v2 = x4[(size_t)(r + 16) * DV + fg];
                f32x4 v3 = x4[(size_t)(r + 24) * DV + fg];
                a0 += v0 * v0; a1 += v1 * v1; a2 += v2 * v2; a3 += v3 * v3;
            }
            for (; r < run_end; r += 8) {
                f32x4 v = x4[(size_t)r * DV + fg];
                a0 += v * v;
            }
            a0 += a1; a2 += a3; a0 += a2;

            red[tid] = a0;
            __syncthreads();
            if (lane < 4) red[tid] += red[tid + 128];
            __syncthreads();
            if (lane < 2) red[tid] += red[tid + 64];
            __syncthreads();
            if (lane == 0) {
                f32x4 s = red[tid] + red[tid + 32];
                float* dst = out + (size_t)g * D_FEAT + fg * 4;
                atomicAdd(dst + 0, s[0]);
                atomicAdd(dst + 1, s[1]);
                atomicAdd(dst + 2, s[2]);
                atomicAdd(dst + 3, s[3]);
            }
            __syncthreads();               // red reused next run
            cur = run_end;
            if (cur < re) g = batch[cur];  // uniform
        }
    }
}

// ---- Kernel F: finalize sqrt(sum / count) -------------------------------
__global__ __launch_bounds__(128) void finalize_kernel(
    const int* __restrict__ off, float* __restrict__ out)
{
    const int g = blockIdx.x;
    const int d = threadIdx.x;
    const int cnt = off[g + 1] - off[g];
    const size_t i = (size_t)g * D_FEAT + d;
    const float v = out[i];
    out[i] = (cnt > 0) ? sqrtf(v / (float)cnt) : 0.f;
}

extern "C" void kernel_launch(void* const* d_in, const int* in_sizes, int n_in,
                              void* d_out, int out_size, void* d_ws, size_t ws_size,
                              hipStream_t stream) {
    const float* x     = (const float*)d_in[0];
    const int*   batch = (const int*)d_in[1];
    float*       out   = (float*)d_out;

    const int N = in_sizes[1];           // 1,000,000 nodes
    const int G = out_size / D_FEAT;     // 4096 graphs

    int* off = (int*)d_ws;               // (G+1) ints

    const int n4 = G * DV;

    seg_offsets_kernel<<<(N + 255) / 256, 256, 0, stream>>>(batch, off, N, G);
    zero_out_kernel<<<(n4 + 255) / 256, 256, 0, stream>>>((f32x4*)out, n4);
    global_powermean_pooling_44126493999223_kernel
        <<<SWEEP_GRID, 256, 0, stream>>>((const f32x4*)x, batch, off, out, N);
    finalize_kernel<<<G, 128, 0, stream>>>(off, out);
}